// Round 15
// baseline (270.444 us; speedup 1.0000x reference)
//
#include <hip/hip_runtime.h>

#define NJ  21
#define FT  6
#define JW  176  // packed per-joint weights: 16 rows x (10w + bias) = 176

// E=1, readlane weight delivery (r12, proven), DIRECT stores, NO output tile,
// NO barriers after weight staging. r13 lesson: occupancy 40->50% was flat at
// VALUBusy ~60% -> not latency-bound; the flush machinery (25 barriers, 1-of-4
// waves active in PUT phases) and its LDS cap are the suspected residue.
// This round cleanly tests write amplification vs barrier cost: jw-only LDS
// (14.8KB) -> 8 blk/CU, f-values die at their store (VGPR ~40, under the
// RA's 64 pin seen in r8-r11).

__device__ __forceinline__ float RL(float v, int l) {
    return __int_as_float(__builtin_amdgcn_readlane(__float_as_int(v), l));
}
#define RW(N,k) ((k) < 64 ? RL(wv##N##_0, (k)) : \
                 (k) < 128 ? RL(wv##N##_1, (k)-64) : RL(wv##N##_2, (k)-128))

// hidden row r (weights k = r*11 + 0..9, bias at r*11+10)
#define HROW(N,P,r) const float h##N##_##r = fmaxf( \
  fmaf(RW(N,(r)*11+9), f##P##_5, fmaf(RW(N,(r)*11+8), f##P##_4, \
  fmaf(RW(N,(r)*11+7), f##P##_3, fmaf(RW(N,(r)*11+6), f##P##_2, \
  fmaf(RW(N,(r)*11+5), f##P##_1, fmaf(RW(N,(r)*11+4), f##P##_0, \
  fmaf(RW(N,(r)*11+3), q##N.w,   fmaf(RW(N,(r)*11+2), q##N.z, \
  fmaf(RW(N,(r)*11+1), q##N.y,   fmaf(RW(N,(r)*11+0), q##N.x, \
  RW(N,(r)*11+10))))))))))), 0.0f);

// output row r (weights k = 110 + r*11 + 0..9, bias at +10)
#define FROW(N,r) const float f##N##_##r = fmaxf( \
  fmaf(RW(N,110+(r)*11+9), h##N##_9, fmaf(RW(N,110+(r)*11+8), h##N##_8, \
  fmaf(RW(N,110+(r)*11+7), h##N##_7, fmaf(RW(N,110+(r)*11+6), h##N##_6, \
  fmaf(RW(N,110+(r)*11+5), h##N##_5, fmaf(RW(N,110+(r)*11+4), h##N##_4, \
  fmaf(RW(N,110+(r)*11+3), h##N##_3, fmaf(RW(N,110+(r)*11+2), h##N##_2, \
  fmaf(RW(N,110+(r)*11+1), h##N##_1, fmaf(RW(N,110+(r)*11+0), h##N##_0, \
  RW(N,110+(r)*11+10))))))))))), 0.0f);

// direct store; f-values die here (no cross-phase liveness, no barriers)
#define STORE_F(N,j) { \
  float2* o2_ = reinterpret_cast<float2*>(op + (j)*FT); \
  o2_[0] = make_float2(f##N##_0, f##N##_1); \
  o2_[1] = make_float2(f##N##_2, f##N##_3); \
  o2_[2] = make_float2(f##N##_4, f##N##_5); }

#define DO_JOINT(j,P,N) \
  const float4 q##N = qv[j]; \
  const float wv##N##_0 = jw[(j)*JW + lane]; \
  const float wv##N##_1 = jw[(j)*JW + 64 + lane]; \
  const float wv##N##_2 = jw[(j)*JW + 128 + lane]; \
  HROW(N,P,0) HROW(N,P,1) HROW(N,P,2) HROW(N,P,3) HROW(N,P,4) \
  HROW(N,P,5) HROW(N,P,6) HROW(N,P,7) HROW(N,P,8) HROW(N,P,9) \
  FROW(N,0) FROW(N,1) FROW(N,2) FROW(N,3) FROW(N,4) FROW(N,5) \
  STORE_F(N,j)

__global__ __launch_bounds__(256) void se_kernel(
    const float* __restrict__ quat,   // [B, 21, 4]
    const float* __restrict__ W1r,    // [10, 4]
    const float* __restrict__ b1r,    // [10]
    const float* __restrict__ W1,     // [20, 10, 10]
    const float* __restrict__ b1,     // [20, 10]
    const float* __restrict__ W2,     // [21, 6, 10]
    const float* __restrict__ b2,     // [21, 6]
    float*       __restrict__ out,    // [B, 126]
    int B)
{
    __shared__ float jw[NJ * JW];     // 14784 B; only LDS -> 8 blocks/CU

    const int tid  = threadIdx.x;
    const int lane = tid & 63;
    const int base = blockIdx.x * 256;

    // ---- stage packed weights (joint j block: 110 W1|b1 then 66 W2|b2) ----
    for (int i = tid; i < 20*110; i += 256) {          // joints 1..20, layer 1
        const int j = i / 110, k = i % 110, r = k / 11, c = k % 11;
        jw[(j+1)*JW + k] = (c < 10) ? W1[j*100 + r*10 + c] : b1[j*10 + r];
    }
    for (int i = tid; i < 20*66; i += 256) {           // joints 1..20, layer 2
        const int j = i / 66, k = i % 66, r = k / 11, c = k % 11;
        jw[(j+1)*JW + 110 + k] = (c < 10) ? W2[(j+1)*60 + r*10 + c]
                                          : b2[(j+1)*6 + r];
    }
    if (tid < 50) {                                    // root layer 1: 5/row
        const int r = tid / 5, c = tid % 5;
        jw[tid] = (c < 4) ? W1r[r*4 + c] : b1r[r];
    }
    if (tid < 66) {                                    // root layer 2 at +50
        const int r = tid / 11, c = tid % 11;
        jw[50 + tid] = (c < 10) ? W2[r*10 + c] : b2[r];
    }
    __syncthreads();

    const int bcl = min(base + tid, B - 1);
    const float4* __restrict__ qv =
        reinterpret_cast<const float4*>(quat) + (size_t)bcl * NJ;
    float* __restrict__ op = out + (size_t)bcl * (NJ * FT);

    // ---- root (joint 0): W1r rows 5 floats (4w+bias at r*5+4); W2 at +50 ----
    const float4 q0 = qv[0];
    const float wv0_0 = jw[lane];
    const float wv0_1 = jw[64 + lane];
    const float wv0_2 = jw[128 + lane];   // referenced by RW's dead branch; folds away
#define H0ROW(r) const float h0_##r = fmaxf( \
    fmaf(RW(0,(r)*5+3), q0.w, fmaf(RW(0,(r)*5+2), q0.z, \
    fmaf(RW(0,(r)*5+1), q0.y, fmaf(RW(0,(r)*5+0), q0.x, RW(0,(r)*5+4))))), 0.0f);
    H0ROW(0) H0ROW(1) H0ROW(2) H0ROW(3) H0ROW(4)
    H0ROW(5) H0ROW(6) H0ROW(7) H0ROW(8) H0ROW(9)
#undef H0ROW
#define F0ROW(r) const float f0_##r = fmaxf( \
    fmaf(RW(0,50+(r)*11+9), h0_9, fmaf(RW(0,50+(r)*11+8), h0_8, \
    fmaf(RW(0,50+(r)*11+7), h0_7, fmaf(RW(0,50+(r)*11+6), h0_6, \
    fmaf(RW(0,50+(r)*11+5), h0_5, fmaf(RW(0,50+(r)*11+4), h0_4, \
    fmaf(RW(0,50+(r)*11+3), h0_3, fmaf(RW(0,50+(r)*11+2), h0_2, \
    fmaf(RW(0,50+(r)*11+1), h0_1, fmaf(RW(0,50+(r)*11+0), h0_0, \
    RW(0,50+(r)*11+10))))))))))), 0.0f);
    F0ROW(0) F0ROW(1) F0ROW(2) F0ROW(3) F0ROW(4) F0ROW(5)
#undef F0ROW
    STORE_F(0,0)

    // ---- DFS over the kinematic tree (<=3 parent feature sets live) ----
    DO_JOINT(1,0,1)    DO_JOINT(4,1,4)    DO_JOINT(7,4,7)    DO_JOINT(10,7,10)
    DO_JOINT(2,0,2)    DO_JOINT(5,2,5)    DO_JOINT(8,5,8)    DO_JOINT(11,8,11)
    DO_JOINT(3,0,3)    DO_JOINT(6,3,6)    DO_JOINT(9,6,9)
    DO_JOINT(12,9,12)  DO_JOINT(15,12,15)
    DO_JOINT(13,9,13)  DO_JOINT(16,13,16) DO_JOINT(18,16,18) DO_JOINT(20,18,20)
    DO_JOINT(14,9,14)  DO_JOINT(17,14,17) DO_JOINT(19,17,19)
}

extern "C" void kernel_launch(void* const* d_in, const int* in_sizes, int n_in,
                              void* d_out, int out_size, void* d_ws, size_t ws_size,
                              hipStream_t stream) {
    const float* quat = (const float*)d_in[0];
    const float* W1r  = (const float*)d_in[1];
    const float* b1r  = (const float*)d_in[2];
    const float* W1   = (const float*)d_in[3];
    const float* b1   = (const float*)d_in[4];
    const float* W2   = (const float*)d_in[5];
    const float* b2   = (const float*)d_in[6];
    float* out = (float*)d_out;

    const int B = in_sizes[0] / (NJ * 4);
    const int blocks = (B + 255) / 256;
    se_kernel<<<blocks, 256, 0, stream>>>(quat, W1r, b1r, W1, b1, W2, b2, out, B);
}

// Round 16
// 202.381 us; speedup vs baseline: 1.3363x; 1.3363x over previous
//
#include <hip/hip_runtime.h>

#define NJ  21
#define FT  6
#define TRS 43   // output tile row stride; odd -> bank-conflict-free
#define TRW 64   // tile rows
#define WRS 12   // W1 row stride: 10w + bias@[10] + pad (48B, 16B-aligned)

// Hybrid weight delivery. r6: all-LDS broadcast -> LDS-pipe bound (204us,
// VALU 30%). r12: all-readlane -> VALU-issue bound (187us, VALU 58%, LDS
// idle). r15: direct stores -> write-amp bound (270us) => tile flush settled.
// This round: layer-1 weights (110/joint) via LDS b128 broadcast (30 uniform
// reads/joint-wave, ~60% of r6's load) and layer-2 (66/joint) via readlane
// (62% fewer RLs than r12, ~30% fewer VALU instrs) -> both pipes work.

__device__ __forceinline__ float RL(float v, int l) {
    return __int_as_float(__builtin_amdgcn_readlane(__float_as_int(v), l));
}
// W2 weight k (0..65) of joint-block N, lane-resident in 2 VGPRs
#define RW2(N,k) ((k) < 64 ? RL(wv##N##_0, (k)) : RL(wv##N##_1, (k)-64))

// relu(dot10 + bias@[10]) from an LDS row (uniform-address b128 broadcasts)
#define F10B(W, a0,a1,a2,a3,a4,a5,a6,a7,a8,a9) \
  fmaxf(fmaf((W)[9],(a9),fmaf((W)[8],(a8),fmaf((W)[7],(a7),fmaf((W)[6],(a6), \
        fmaf((W)[5],(a5),fmaf((W)[4],(a4),fmaf((W)[3],(a3),fmaf((W)[2],(a2), \
        fmaf((W)[1],(a1),fmaf((W)[0],(a0),(W)[10])))))))))), 0.0f)

#define HROW(N,P,j,r) const float h##N##_##r = \
  F10B(w1s + (((j)-1)*10 + (r))*WRS, \
       q##N.x, q##N.y, q##N.z, q##N.w, \
       f##P##_0, f##P##_1, f##P##_2, f##P##_3, f##P##_4, f##P##_5);

// output row r via readlane (weights k = r*11 + 0..9, bias at +10; max k=65)
#define FROW(N,r) const float f##N##_##r = fmaxf( \
  fmaf(RW2(N,(r)*11+9), h##N##_9, fmaf(RW2(N,(r)*11+8), h##N##_8, \
  fmaf(RW2(N,(r)*11+7), h##N##_7, fmaf(RW2(N,(r)*11+6), h##N##_6, \
  fmaf(RW2(N,(r)*11+5), h##N##_5, fmaf(RW2(N,(r)*11+4), h##N##_4, \
  fmaf(RW2(N,(r)*11+3), h##N##_3, fmaf(RW2(N,(r)*11+2), h##N##_2, \
  fmaf(RW2(N,(r)*11+1), h##N##_1, fmaf(RW2(N,(r)*11+0), h##N##_0, \
  RW2(N,(r)*11+10))))))))))), 0.0f);

#define DO_JOINT(j,P,N) \
  const float4 q##N = qv[j]; \
  const float wv##N##_0 = w2l[(j)*72 + lane]; \
  const float wv##N##_1 = w2l[(j)*72 + 64 + lane]; \
  HROW(N,P,j,0) HROW(N,P,j,1) HROW(N,P,j,2) HROW(N,P,j,3) HROW(N,P,j,4) \
  HROW(N,P,j,5) HROW(N,P,j,6) HROW(N,P,j,7) HROW(N,P,j,8) HROW(N,P,j,9) \
  FROW(N,0) FROW(N,1) FROW(N,2) FROW(N,3) FROW(N,4) FROW(N,5)

#define PUT6(p, X) { (p)[0]=f##X##_0; (p)[1]=f##X##_1; (p)[2]=f##X##_2; \
                     (p)[3]=f##X##_3; (p)[4]=f##X##_4; (p)[5]=f##X##_5; }

// Quarter flush: wave q PUTs its 64 rows, then ALL threads stream them out.
#define QFLUSH(k, q, N0,N1,N2,N3,N4,N5,N6) \
  __syncthreads(); \
  if ((tid >> 6) == (q)) { \
    float* tr_ = tile + (tid & 63) * TRS; \
    PUT6(tr_+0,  N0) PUT6(tr_+6,  N1) PUT6(tr_+12, N2) PUT6(tr_+18, N3) \
    PUT6(tr_+24, N4) PUT6(tr_+30, N5) PUT6(tr_+36, N6) \
  } \
  __syncthreads(); \
  for (int i_ = tid; i_ < TRW*42; i_ += 256) { \
    const int row_ = i_ / 42, col_ = i_ - row_ * 42; \
    out[(size_t)(base + (q)*TRW + row_) * 126 + (k)*42 + col_] = \
        tile[row_ * TRS + col_]; \
  }

#define CHUNK_FLUSH(k, N0,N1,N2,N3,N4,N5,N6) \
  QFLUSH(k, 0, N0,N1,N2,N3,N4,N5,N6) \
  QFLUSH(k, 1, N0,N1,N2,N3,N4,N5,N6) \
  QFLUSH(k, 2, N0,N1,N2,N3,N4,N5,N6) \
  QFLUSH(k, 3, N0,N1,N2,N3,N4,N5,N6)

__global__ __launch_bounds__(256, 4) void se_kernel(
    const float* __restrict__ quat,   // [B, 21, 4]
    const float* __restrict__ W1r,    // [10, 4]
    const float* __restrict__ b1r,    // [10]
    const float* __restrict__ W1,     // [20, 10, 10]
    const float* __restrict__ b1,     // [20, 10]
    const float* __restrict__ W2,     // [21, 6, 10]
    const float* __restrict__ b2,     // [21, 6]
    float*       __restrict__ out,    // [B, 126]
    int B)
{
    __shared__ float rootw[64];            //  256 B: root layer1, r*5+c (4w+b)
    __shared__ __align__(16) float w1s[200*WRS];  // 9600 B: W1 rows, bias@[10]
    __shared__ float w2l[21*72 + 64];      // 6560 B: W2+b2, 66/joint, stride 72
    __shared__ float tile[TRW*TRS];        // 11008 B -> total ~27.4 KB, 5 blk/CU

    const int tid  = threadIdx.x;
    const int lane = tid & 63;
    const int base = blockIdx.x * 256;

    // ---- stage weights ----
    for (int i = tid; i < 2000; i += 256) {            // W1 joints 1..20
        const int row = i / 10, c = i % 10;
        w1s[row*WRS + c] = W1[i];
    }
    for (int i = tid; i < 200; i += 256) w1s[i*WRS + 10] = b1[i];
    for (int i = tid; i < 1260; i += 256) {            // W2 all joints
        const int j = i / 60, k = i % 60, r = k / 10, c = k % 10;
        w2l[j*72 + r*11 + c] = W2[i];
    }
    for (int i = tid; i < 126; i += 256)               // b2 all joints
        w2l[(i/6)*72 + (i%6)*11 + 10] = b2[i];
    if (tid < 50) {                                    // root layer1: 5/row
        const int r = tid / 5, c = tid % 5;
        rootw[tid] = (c < 4) ? W1r[r*4 + c] : b1r[r];
    }
    __syncthreads();

    const int bcl = min(base + tid, B - 1);
    const float4* __restrict__ qv =
        reinterpret_cast<const float4*>(quat) + (size_t)bcl * NJ;

    // ---- chunk 0: joints 0..6 ----
    const float4 q0 = qv[0];
    const float rw0   = rootw[lane];
    const float wv0_0 = w2l[lane];
    const float wv0_1 = w2l[64 + lane];
#define H0ROW(r) const float h0_##r = fmaxf( \
    fmaf(RL(rw0,(r)*5+3), q0.w, fmaf(RL(rw0,(r)*5+2), q0.z, \
    fmaf(RL(rw0,(r)*5+1), q0.y, fmaf(RL(rw0,(r)*5+0), q0.x, \
    RL(rw0,(r)*5+4))))), 0.0f);
    H0ROW(0) H0ROW(1) H0ROW(2) H0ROW(3) H0ROW(4)
    H0ROW(5) H0ROW(6) H0ROW(7) H0ROW(8) H0ROW(9)
#undef H0ROW
    FROW(0,0) FROW(0,1) FROW(0,2) FROW(0,3) FROW(0,4) FROW(0,5)

    DO_JOINT(1,0,1)  DO_JOINT(2,0,2)  DO_JOINT(3,0,3)
    DO_JOINT(4,1,4)  DO_JOINT(5,2,5)  DO_JOINT(6,3,6)
    CHUNK_FLUSH(0, 0,1,2,3,4,5,6)

    // ---- chunk 1: joints 7..13 ----
    DO_JOINT(7,4,7)   DO_JOINT(8,5,8)   DO_JOINT(9,6,9)
    DO_JOINT(10,7,10) DO_JOINT(11,8,11)
    DO_JOINT(12,9,12) DO_JOINT(13,9,13)
    CHUNK_FLUSH(1, 7,8,9,10,11,12,13)

    // ---- chunk 2: joints 14..20 ----
    DO_JOINT(14,9,14)  DO_JOINT(15,12,15) DO_JOINT(16,13,16)
    DO_JOINT(17,14,17) DO_JOINT(18,16,18)
    DO_JOINT(19,17,19) DO_JOINT(20,18,20)
    CHUNK_FLUSH(2, 14,15,16,17,18,19,20)
}

extern "C" void kernel_launch(void* const* d_in, const int* in_sizes, int n_in,
                              void* d_out, int out_size, void* d_ws, size_t ws_size,
                              hipStream_t stream) {
    const float* quat = (const float*)d_in[0];
    const float* W1r  = (const float*)d_in[1];
    const float* b1r  = (const float*)d_in[2];
    const float* W1   = (const float*)d_in[3];
    const float* b1   = (const float*)d_in[4];
    const float* W2   = (const float*)d_in[5];
    const float* b2   = (const float*)d_in[6];
    float* out = (float*)d_out;

    const int B = in_sizes[0] / (NJ * 4);
    const int blocks = (B + 255) / 256;
    se_kernel<<<blocks, 256, 0, stream>>>(quat, W1r, b1r, W1, b1, W2, b2, out, B);
}

// Round 17
// 198.416 us; speedup vs baseline: 1.3630x; 1.0200x over previous
//
#include <hip/hip_runtime.h>

#define NJ  21
#define FT  6
#define TRS 43   // output tile row stride; odd -> bank-conflict-free
#define TRW 64   // tile rows
#define WRS 12   // W2 row stride: 10w + bias@[10] + pad (48B, 16B-aligned)
#define J1S 112  // per-joint L1 pack: 110 (10 rows x (10w+bias)) + pad

// Balanced dual-pipe weight delivery, calibrated by r6/r12/r16 measurements:
//   r6  all-LDS  (48 rd/joint): 204us, LDS-bound
//   r16 L1-LDS   (32 rd/joint): 202us, LDS-bound still
//   r12 all-RL   ( 3 rd/joint): 187us, VALU-issue-bound (176 RL/joint)
// => give the SMALL layer to LDS: L1 (110 w) via readlane (110 RL), L2 (66 w)
// via uniform ds_read_b128 broadcast (18 rd/joint, under saturation).
// VALU instr/joint 368->302 (-18%), RL -37%, LDS ~28us (hideable under VALU).
// E=1, r13 tile-64 flush structure, liveness unchanged (VGPR ~40-56).

__device__ __forceinline__ float RL(float v, int l) {
    return __int_as_float(__builtin_amdgcn_readlane(__float_as_int(v), l));
}
// L1 weight k (0..109) of joint-block N, lane-resident in 2 VGPRs
#define RW1(N,k) ((k) < 64 ? RL(wv##N##_0, (k)) : RL(wv##N##_1, (k)-64))

// hidden row r via readlane (weights k = r*11 + 0..9, bias at r*11+10)
#define HROW(N,P,r) const float h##N##_##r = fmaxf( \
  fmaf(RW1(N,(r)*11+9), f##P##_5, fmaf(RW1(N,(r)*11+8), f##P##_4, \
  fmaf(RW1(N,(r)*11+7), f##P##_3, fmaf(RW1(N,(r)*11+6), f##P##_2, \
  fmaf(RW1(N,(r)*11+5), f##P##_1, fmaf(RW1(N,(r)*11+4), f##P##_0, \
  fmaf(RW1(N,(r)*11+3), q##N.w,   fmaf(RW1(N,(r)*11+2), q##N.z, \
  fmaf(RW1(N,(r)*11+1), q##N.y,   fmaf(RW1(N,(r)*11+0), q##N.x, \
  RW1(N,(r)*11+10))))))))))), 0.0f);

// relu(dot10 + bias@[10]) from an LDS row (uniform-address b128 broadcasts)
#define F10B(W, a0,a1,a2,a3,a4,a5,a6,a7,a8,a9) \
  fmaxf(fmaf((W)[9],(a9),fmaf((W)[8],(a8),fmaf((W)[7],(a7),fmaf((W)[6],(a6), \
        fmaf((W)[5],(a5),fmaf((W)[4],(a4),fmaf((W)[3],(a3),fmaf((W)[2],(a2), \
        fmaf((W)[1],(a1),fmaf((W)[0],(a0),(W)[10])))))))))), 0.0f)

// output row r via LDS broadcast (W2 row j*6+r)
#define FROW(N,j,r) const float f##N##_##r = \
  F10B(w2s + ((j)*6 + (r))*WRS, \
       h##N##_0, h##N##_1, h##N##_2, h##N##_3, h##N##_4, \
       h##N##_5, h##N##_6, h##N##_7, h##N##_8, h##N##_9);

#define DO_JOINT(j,P,N) \
  const float4 q##N = qv[j]; \
  const float wv##N##_0 = jw1[(j)*J1S + lane]; \
  const float wv##N##_1 = jw1[(j)*J1S + 64 + lane]; \
  HROW(N,P,0) HROW(N,P,1) HROW(N,P,2) HROW(N,P,3) HROW(N,P,4) \
  HROW(N,P,5) HROW(N,P,6) HROW(N,P,7) HROW(N,P,8) HROW(N,P,9) \
  FROW(N,j,0) FROW(N,j,1) FROW(N,j,2) FROW(N,j,3) FROW(N,j,4) FROW(N,j,5)

#define PUT6(p, X) { (p)[0]=f##X##_0; (p)[1]=f##X##_1; (p)[2]=f##X##_2; \
                     (p)[3]=f##X##_3; (p)[4]=f##X##_4; (p)[5]=f##X##_5; }

// Quarter flush: wave q PUTs its 64 rows, then ALL threads stream them out.
#define QFLUSH(k, q, N0,N1,N2,N3,N4,N5,N6) \
  __syncthreads(); \
  if ((tid >> 6) == (q)) { \
    float* tr_ = tile + (tid & 63) * TRS; \
    PUT6(tr_+0,  N0) PUT6(tr_+6,  N1) PUT6(tr_+12, N2) PUT6(tr_+18, N3) \
    PUT6(tr_+24, N4) PUT6(tr_+30, N5) PUT6(tr_+36, N6) \
  } \
  __syncthreads(); \
  for (int i_ = tid; i_ < TRW*42; i_ += 256) { \
    const int row_ = i_ / 42, col_ = i_ - row_ * 42; \
    out[(size_t)(base + (q)*TRW + row_) * 126 + (k)*42 + col_] = \
        tile[row_ * TRS + col_]; \
  }

#define CHUNK_FLUSH(k, N0,N1,N2,N3,N4,N5,N6) \
  QFLUSH(k, 0, N0,N1,N2,N3,N4,N5,N6) \
  QFLUSH(k, 1, N0,N1,N2,N3,N4,N5,N6) \
  QFLUSH(k, 2, N0,N1,N2,N3,N4,N5,N6) \
  QFLUSH(k, 3, N0,N1,N2,N3,N4,N5,N6)

__global__ __launch_bounds__(256, 4) void se_kernel(
    const float* __restrict__ quat,   // [B, 21, 4]
    const float* __restrict__ W1r,    // [10, 4]
    const float* __restrict__ b1r,    // [10]
    const float* __restrict__ W1,     // [20, 10, 10]
    const float* __restrict__ b1,     // [20, 10]
    const float* __restrict__ W2,     // [21, 6, 10]
    const float* __restrict__ b2,     // [21, 6]
    float*       __restrict__ out,    // [B, 126]
    int B)
{
    __shared__ float jw1[NJ * J1S];               // 9408 B: L1 packs (RL path)
    __shared__ __align__(16) float w2s[126*WRS];  // 6048 B: W2 rows (LDS path)
    __shared__ float tile[TRW * TRS];             // 11008 B -> ~26.5 KB total

    const int tid  = threadIdx.x;
    const int lane = tid & 63;
    const int base = blockIdx.x * 256;

    // ---- stage weights ----
    for (int i = tid; i < 20*110; i += 256) {      // L1 joints 1..20
        const int j = i / 110, k = i % 110, r = k / 11, c = k % 11;
        jw1[(j+1)*J1S + k] = (c < 10) ? W1[j*100 + r*10 + c] : b1[j*10 + r];
    }
    if (tid < 50) {                                // root L1: 5/row (4w+bias)
        const int r = tid / 5, c = tid % 5;
        jw1[tid] = (c < 4) ? W1r[r*4 + c] : b1r[r];
    }
    for (int i = tid; i < 1260; i += 256) {        // W2 all joints
        const int row = i / 10, c = i % 10;
        w2s[row*WRS + c] = W2[i];
    }
    for (int i = tid; i < 126; i += 256) w2s[i*WRS + 10] = b2[i];
    __syncthreads();

    const int bcl = min(base + tid, B - 1);
    const float4* __restrict__ qv =
        reinterpret_cast<const float4*>(quat) + (size_t)bcl * NJ;

    // ---- chunk 0: joints 0..6 ----
    const float4 q0 = qv[0];
    const float wv0_0 = jw1[lane];
    const float wv0_1 = jw1[64 + lane];            // RW1 dead-branch ref; folds
#define H0ROW(r) const float h0_##r = fmaxf( \
    fmaf(RW1(0,(r)*5+3), q0.w, fmaf(RW1(0,(r)*5+2), q0.z, \
    fmaf(RW1(0,(r)*5+1), q0.y, fmaf(RW1(0,(r)*5+0), q0.x, \
    RW1(0,(r)*5+4))))), 0.0f);
    H0ROW(0) H0ROW(1) H0ROW(2) H0ROW(3) H0ROW(4)
    H0ROW(5) H0ROW(6) H0ROW(7) H0ROW(8) H0ROW(9)
#undef H0ROW
    FROW(0,0,0) FROW(0,0,1) FROW(0,0,2) FROW(0,0,3) FROW(0,0,4) FROW(0,0,5)

    DO_JOINT(1,0,1)  DO_JOINT(2,0,2)  DO_JOINT(3,0,3)
    DO_JOINT(4,1,4)  DO_JOINT(5,2,5)  DO_JOINT(6,3,6)
    CHUNK_FLUSH(0, 0,1,2,3,4,5,6)

    // ---- chunk 1: joints 7..13 ----
    DO_JOINT(7,4,7)   DO_JOINT(8,5,8)   DO_JOINT(9,6,9)
    DO_JOINT(10,7,10) DO_JOINT(11,8,11)
    DO_JOINT(12,9,12) DO_JOINT(13,9,13)
    CHUNK_FLUSH(1, 7,8,9,10,11,12,13)

    // ---- chunk 2: joints 14..20 ----
    DO_JOINT(14,9,14)  DO_JOINT(15,12,15) DO_JOINT(16,13,16)
    DO_JOINT(17,14,17) DO_JOINT(18,16,18)
    DO_JOINT(19,17,19) DO_JOINT(20,18,20)
    CHUNK_FLUSH(2, 14,15,16,17,18,19,20)
}

extern "C" void kernel_launch(void* const* d_in, const int* in_sizes, int n_in,
                              void* d_out, int out_size, void* d_ws, size_t ws_size,
                              hipStream_t stream) {
    const float* quat = (const float*)d_in[0];
    const float* W1r  = (const float*)d_in[1];
    const float* b1r  = (const float*)d_in[2];
    const float* W1   = (const float*)d_in[3];
    const float* b1   = (const float*)d_in[4];
    const float* W2   = (const float*)d_in[5];
    const float* b2   = (const float*)d_in[6];
    float* out = (float*)d_out;

    const int B = in_sizes[0] / (NJ * 4);
    const int blocks = (B + 255) / 256;
    se_kernel<<<blocks, 256, 0, stream>>>(quat, W1r, b1r, W1, b1, W2, b2, out, B);
}